// Round 2
// baseline (298.509 us; speedup 1.0000x reference)
//
#include <hip/hip_runtime.h>
#include <hip/hip_bf16.h>

// Problem constants (from reference): B=4, G=3, p=16, N=256, C=768, H=12, D=64
#define Bc 4
#define Gc 3
#define Pc 16
#define Nc 256
#define Cc_ 768
#define Hc 12
#define Dc 64
#define Mrows (Bc*Gc*Nc)      // 3072 tokens
#define KVcols (2*Cc_)        // 1536

// ---------------------------------------------------------------------------
// Tiled fp32 GEMM:  C[m][n] = sum_k A[m][k] * W[n][k]  (+ bias[n])
// A: (M,K) row-major, W: (N,K) row-major (i.e. torch Linear weight), C: (M,N)
// 64x64 tile, 256 threads, each thread 4x4 micro-tile, K-step 16.
// LDS stored k-major ([k][m]) so compute reads are float4 along m/n.
// ---------------------------------------------------------------------------
__global__ __launch_bounds__(256) void gemm_nt_64(
    const float* __restrict__ A, const float* __restrict__ W,
    float* __restrict__ C, const float* __restrict__ bias,
    int M, int Nn, int K)
{
    __shared__ float As[16][68];   // [k][m], pad keeps float4 alignment, 2-way max
    __shared__ float Bs[16][68];   // [k][n]

    const int tid  = threadIdx.x;
    const int m0   = blockIdx.y << 6;
    const int n0   = blockIdx.x << 6;
    const int tx   = tid & 15;          // n sub-tile
    const int ty   = tid >> 4;          // m sub-tile
    const int lrow = tid >> 2;          // 0..63 (row loaded by this thread)
    const int lk4  = (tid & 3) << 2;    // 0,4,8,12 (k offset)

    const float* Ap = A + (size_t)(m0 + lrow) * K + lk4;
    const float* Wp = W + (size_t)(n0 + lrow) * K + lk4;

    float acc[4][4] = {};

    for (int k0 = 0; k0 < K; k0 += 16) {
        const float4 av = *(const float4*)(Ap + k0);
        const float4 bv = *(const float4*)(Wp + k0);
        __syncthreads();   // previous iteration's LDS reads done
        As[lk4+0][lrow] = av.x; As[lk4+1][lrow] = av.y;
        As[lk4+2][lrow] = av.z; As[lk4+3][lrow] = av.w;
        Bs[lk4+0][lrow] = bv.x; Bs[lk4+1][lrow] = bv.y;
        Bs[lk4+2][lrow] = bv.z; Bs[lk4+3][lrow] = bv.w;
        __syncthreads();
        #pragma unroll
        for (int kk = 0; kk < 16; ++kk) {
            const float4 a4 = *(const float4*)&As[kk][ty << 2];
            const float4 b4 = *(const float4*)&Bs[kk][tx << 2];
            const float a[4] = {a4.x, a4.y, a4.z, a4.w};
            const float b[4] = {b4.x, b4.y, b4.z, b4.w};
            #pragma unroll
            for (int i = 0; i < 4; ++i)
                #pragma unroll
                for (int j = 0; j < 4; ++j)
                    acc[i][j] = fmaf(a[i], b[j], acc[i][j]);
        }
    }

    float bb[4] = {0.f, 0.f, 0.f, 0.f};
    if (bias) {
        const float4 b4 = *(const float4*)&bias[n0 + (tx << 2)];
        bb[0] = b4.x; bb[1] = b4.y; bb[2] = b4.z; bb[3] = b4.w;
    }
    #pragma unroll
    for (int i = 0; i < 4; ++i) {
        const int mrow = m0 + (ty << 2) + i;
        float4 r;
        r.x = acc[i][0] + bb[0];
        r.y = acc[i][1] + bb[1];
        r.z = acc[i][2] + bb[2];
        r.w = acc[i][3] + bb[3];
        *(float4*)&C[(size_t)mrow * Nn + n0 + (tx << 2)] = r;
    }
}

// ---------------------------------------------------------------------------
// Attention: one block (256 thr = 4 waves) per token t = (g*B+b)*N + n.
// Each wave handles heads {w, w+4, w+8}. Per head:
//   scores: lane = (j = lane&31, dhalf = lane>>5), partial dot over 32 dims,
//           combine with shfl_xor(32); softmax via shfl reduction.
//   PV:     lane = output dim d (0..63), p[j] broadcast via shfl.
// K/V are gathered from the per-token KV projection via the triplane index map.
// ---------------------------------------------------------------------------
__global__ __launch_bounds__(256) void attn_kernel(
    const float* __restrict__ Q,    // (Mrows, C) in x-order rows (b,g,n)
    const float* __restrict__ KV,   // (Mrows, 2C) in x-order rows; [0,C)=k, [C,2C)=v
    float* __restrict__ Oa)         // (Mrows, C) in out-order rows (g,b,n)
{
    const int t  = blockIdx.x;          // (g*4 + b)*256 + n
    const int g  = t >> 10;
    const int b  = (t >> 8) & 3;
    const int n  = t & 255;
    const int a  = n >> 4;
    const int bc = n & 15;

    __shared__ float qs[Cc_];
    __shared__ int   rows[32];

    const int qrow = (b * Gc + g) * Nc + n;   // x-order row of this token
    for (int i = threadIdx.x; i < Cc_; i += 256)
        qs[i] = Q[(size_t)qrow * Cc_ + i];

    if (threadIdx.x < 32) {
        const int j = threadIdx.x;
        int g1 = g + 1; if (g1 >= 3) g1 -= 3;
        int g2 = g + 2; if (g2 >= 3) g2 -= 3;
        rows[j] = (j < 16) ? ((b * Gc + g1) * Nc + a * 16 + j)
                           : ((b * Gc + g2) * Nc + (j - 16) * 16 + bc);
    }
    __syncthreads();

    const int wave = threadIdx.x >> 6;
    const int lane = threadIdx.x & 63;
    const int j    = lane & 31;
    const int dh   = lane >> 5;
    const size_t kvrow = (size_t)rows[j] * KVcols;

    for (int hh = 0; hh < 3; ++hh) {
        const int h = wave + hh * 4;          // heads 0..11
        // ---- scores ----
        const float* kp = KV + kvrow + h * Dc + dh * 32;
        const float* qp = qs + h * Dc + dh * 32;
        float s = 0.f;
        #pragma unroll
        for (int dd = 0; dd < 32; ++dd) s = fmaf(qp[dd], kp[dd], s);
        s += __shfl_xor(s, 32);               // full 64-dim dot (dup in halves)
        s *= 0.125f;                          // 1/sqrt(64)

        // ---- softmax over 32 ctx (halves hold identical values) ----
        float m = s;
        #pragma unroll
        for (int off = 16; off >= 1; off >>= 1) m = fmaxf(m, __shfl_xor(m, off));
        const float e = __expf(s - m);
        float l = e;
        #pragma unroll
        for (int off = 16; off >= 1; off >>= 1) l += __shfl_xor(l, off);
        const float pr = e / l;

        // ---- PV: lane = output dim ----
        float o = 0.f;
        #pragma unroll 8
        for (int jj = 0; jj < 32; ++jj) {
            const float pj = __shfl(pr, jj);  // p[jj] lives on lane jj
            const int rr = rows[jj];
            o = fmaf(pj, KV[(size_t)rr * KVcols + Cc_ + h * Dc + lane], o);
        }
        Oa[(size_t)t * Cc_ + h * Dc + lane] = o;
    }
}

extern "C" void kernel_launch(void* const* d_in, const int* in_sizes, int n_in,
                              void* d_out, int out_size, void* d_ws, size_t ws_size,
                              hipStream_t stream) {
    const float* x   = (const float*)d_in[0];   // (B,G,N,C)
    const float* wq  = (const float*)d_in[1];   // (C,C)
    const float* wkv = (const float*)d_in[2];   // (2C,C)
    const float* pw  = (const float*)d_in[3];   // (C,C)
    const float* pb  = (const float*)d_in[4];   // (C,)
    float* out = (float*)d_out;

    float* Q   = (float*)d_ws;                  // 3072*768
    float* KV  = Q  + (size_t)Mrows * Cc_;      // 3072*1536
    float* ATT = KV + (size_t)Mrows * KVcols;   // 3072*768

    const dim3 blk(256);

    // Q = x @ wq^T      (x-order rows)
    gemm_nt_64<<<dim3(Cc_ / 64, Mrows / 64), blk, 0, stream>>>(
        x, wq, Q, nullptr, Mrows, Cc_, Cc_);
    // KV = x @ w_kv^T   (x-order rows) — projects each token ONCE (32x less
    // work than projecting the materialized context)
    gemm_nt_64<<<dim3(KVcols / 64, Mrows / 64), blk, 0, stream>>>(
        x, wkv, KV, nullptr, Mrows, KVcols, Cc_);
    // attention with gathered K/V, writes out-order rows
    attn_kernel<<<dim3(Mrows), blk, 0, stream>>>(Q, KV, ATT);
    // out = ATT @ proj_w^T + proj_b   (d_out layout == flat (g,b,n,c))
    gemm_nt_64<<<dim3(Cc_ / 64, Mrows / 64), blk, 0, stream>>>(
        ATT, pw, out, pb, Mrows, Cc_, Cc_);
}

// Round 3
// 298.229 us; speedup vs baseline: 1.0009x; 1.0009x over previous
//
#include <hip/hip_runtime.h>
#include <hip/hip_bf16.h>

// Problem constants (from reference): B=4, G=3, p=16, N=256, C=768, H=12, D=64
#define Bc 4
#define Gc 3
#define Pc 16
#define Nc 256
#define Cc_ 768
#define Hc 12
#define Dc 64
#define Mrows (Bc*Gc*Nc)      // 3072 tokens
#define KVcols (2*Cc_)        // 1536

// ---------------------------------------------------------------------------
// Tiled fp32 GEMM:  C[m][n] = sum_k A[m][k] * W[n][k]  (+ bias[n])
// A: (M,K) row-major, W: (N,K) row-major (i.e. torch Linear weight), C: (M,N)
// 64x64 tile, 256 threads, each thread 4x4 micro-tile, K-step 16.
// LDS stored k-major ([k][m]) so compute reads are float4 along m/n.
// ---------------------------------------------------------------------------
__global__ __launch_bounds__(256) void gemm_nt_64(
    const float* __restrict__ A, const float* __restrict__ W,
    float* __restrict__ C, const float* __restrict__ bias,
    int M, int Nn, int K)
{
    __shared__ float As[16][68];   // [k][m], pad keeps float4 alignment, 2-way max
    __shared__ float Bs[16][68];   // [k][n]

    const int tid  = threadIdx.x;
    const int m0   = blockIdx.y << 6;
    const int n0   = blockIdx.x << 6;
    const int tx   = tid & 15;          // n sub-tile
    const int ty   = tid >> 4;          // m sub-tile
    const int lrow = tid >> 2;          // 0..63 (row loaded by this thread)
    const int lk4  = (tid & 3) << 2;    // 0,4,8,12 (k offset)

    const float* Ap = A + (size_t)(m0 + lrow) * K + lk4;
    const float* Wp = W + (size_t)(n0 + lrow) * K + lk4;

    float acc[4][4] = {};

    for (int k0 = 0; k0 < K; k0 += 16) {
        const float4 av = *(const float4*)(Ap + k0);
        const float4 bv = *(const float4*)(Wp + k0);
        __syncthreads();   // previous iteration's LDS reads done
        As[lk4+0][lrow] = av.x; As[lk4+1][lrow] = av.y;
        As[lk4+2][lrow] = av.z; As[lk4+3][lrow] = av.w;
        Bs[lk4+0][lrow] = bv.x; Bs[lk4+1][lrow] = bv.y;
        Bs[lk4+2][lrow] = bv.z; Bs[lk4+3][lrow] = bv.w;
        __syncthreads();
        #pragma unroll
        for (int kk = 0; kk < 16; ++kk) {
            const float4 a4 = *(const float4*)&As[kk][ty << 2];
            const float4 b4 = *(const float4*)&Bs[kk][tx << 2];
            const float a[4] = {a4.x, a4.y, a4.z, a4.w};
            const float b[4] = {b4.x, b4.y, b4.z, b4.w};
            #pragma unroll
            for (int i = 0; i < 4; ++i)
                #pragma unroll
                for (int j = 0; j < 4; ++j)
                    acc[i][j] = fmaf(a[i], b[j], acc[i][j]);
        }
    }

    float bb[4] = {0.f, 0.f, 0.f, 0.f};
    if (bias) {
        const float4 b4 = *(const float4*)&bias[n0 + (tx << 2)];
        bb[0] = b4.x; bb[1] = b4.y; bb[2] = b4.z; bb[3] = b4.w;
    }
    #pragma unroll
    for (int i = 0; i < 4; ++i) {
        const int mrow = m0 + (ty << 2) + i;
        float4 r;
        r.x = acc[i][0] + bb[0];
        r.y = acc[i][1] + bb[1];
        r.z = acc[i][2] + bb[2];
        r.w = acc[i][3] + bb[3];
        *(float4*)&C[(size_t)mrow * Nn + n0 + (tx << 2)] = r;
    }
}

// ---------------------------------------------------------------------------
// Attention: one block (256 thr = 4 waves) per token t = (g*B+b)*N + n.
// Each wave handles heads {w, w+4, w+8}. Per head:
//   scores: lane = (j = lane&31, dhalf = lane>>5), partial dot over 32 dims,
//           combine with shfl_xor(32); softmax via shfl reduction.
//   PV:     lane = output dim d (0..63), p[j] broadcast via shfl.
// K/V are gathered from the per-token KV projection via the triplane index map.
// ---------------------------------------------------------------------------
__global__ __launch_bounds__(256) void attn_kernel(
    const float* __restrict__ Q,    // (Mrows, C) in x-order rows (b,g,n)
    const float* __restrict__ KV,   // (Mrows, 2C) in x-order rows; [0,C)=k, [C,2C)=v
    float* __restrict__ Oa)         // (Mrows, C) in out-order rows (g,b,n)
{
    const int t  = blockIdx.x;          // (g*4 + b)*256 + n
    const int g  = t >> 10;
    const int b  = (t >> 8) & 3;
    const int n  = t & 255;
    const int a  = n >> 4;
    const int bc = n & 15;

    __shared__ float qs[Cc_];
    __shared__ int   rows[32];

    const int qrow = (b * Gc + g) * Nc + n;   // x-order row of this token
    for (int i = threadIdx.x; i < Cc_; i += 256)
        qs[i] = Q[(size_t)qrow * Cc_ + i];

    if (threadIdx.x < 32) {
        const int j = threadIdx.x;
        int g1 = g + 1; if (g1 >= 3) g1 -= 3;
        int g2 = g + 2; if (g2 >= 3) g2 -= 3;
        rows[j] = (j < 16) ? ((b * Gc + g1) * Nc + a * 16 + j)
                           : ((b * Gc + g2) * Nc + (j - 16) * 16 + bc);
    }
    __syncthreads();

    const int wave = threadIdx.x >> 6;
    const int lane = threadIdx.x & 63;
    const int j    = lane & 31;
    const int dh   = lane >> 5;
    const size_t kvrow = (size_t)rows[j] * KVcols;

    for (int hh = 0; hh < 3; ++hh) {
        const int h = wave + hh * 4;          // heads 0..11
        // ---- scores ----
        const float* kp = KV + kvrow + h * Dc + dh * 32;
        const float* qp = qs + h * Dc + dh * 32;
        float s = 0.f;
        #pragma unroll
        for (int dd = 0; dd < 32; ++dd) s = fmaf(qp[dd], kp[dd], s);
        s += __shfl_xor(s, 32);               // full 64-dim dot (dup in halves)
        s *= 0.125f;                          // 1/sqrt(64)

        // ---- softmax over 32 ctx (halves hold identical values) ----
        float m = s;
        #pragma unroll
        for (int off = 16; off >= 1; off >>= 1) m = fmaxf(m, __shfl_xor(m, off));
        const float e = __expf(s - m);
        float l = e;
        #pragma unroll
        for (int off = 16; off >= 1; off >>= 1) l += __shfl_xor(l, off);
        const float pr = e / l;

        // ---- PV: lane = output dim ----
        float o = 0.f;
        #pragma unroll 8
        for (int jj = 0; jj < 32; ++jj) {
            const float pj = __shfl(pr, jj);  // p[jj] lives on lane jj
            const int rr = rows[jj];
            o = fmaf(pj, KV[(size_t)rr * KVcols + Cc_ + h * Dc + lane], o);
        }
        Oa[(size_t)t * Cc_ + h * Dc + lane] = o;
    }
}

extern "C" void kernel_launch(void* const* d_in, const int* in_sizes, int n_in,
                              void* d_out, int out_size, void* d_ws, size_t ws_size,
                              hipStream_t stream) {
    const float* x   = (const float*)d_in[0];   // (B,G,N,C)
    const float* wq  = (const float*)d_in[1];   // (C,C)
    const float* wkv = (const float*)d_in[2];   // (2C,C)
    const float* pw  = (const float*)d_in[3];   // (C,C)
    const float* pb  = (const float*)d_in[4];   // (C,)
    float* out = (float*)d_out;

    float* Q   = (float*)d_ws;                  // 3072*768
    float* KV  = Q  + (size_t)Mrows * Cc_;      // 3072*1536
    float* ATT = KV + (size_t)Mrows * KVcols;   // 3072*768

    const dim3 blk(256);

    // Q = x @ wq^T      (x-order rows)
    gemm_nt_64<<<dim3(Cc_ / 64, Mrows / 64), blk, 0, stream>>>(
        x, wq, Q, nullptr, Mrows, Cc_, Cc_);
    // KV = x @ w_kv^T   (x-order rows) — projects each token ONCE (32x less
    // work than projecting the materialized context)
    gemm_nt_64<<<dim3(KVcols / 64, Mrows / 64), blk, 0, stream>>>(
        x, wkv, KV, nullptr, Mrows, KVcols, Cc_);
    // attention with gathered K/V, writes out-order rows
    attn_kernel<<<dim3(Mrows), blk, 0, stream>>>(Q, KV, ATT);
    // out = ATT @ proj_w^T + proj_b   (d_out layout == flat (g,b,n,c))
    gemm_nt_64<<<dim3(Cc_ / 64, Mrows / 64), blk, 0, stream>>>(
        ATT, pw, out, pb, Mrows, Cc_, Cc_);
}

// Round 4
// 297.831 us; speedup vs baseline: 1.0023x; 1.0013x over previous
//
#include <hip/hip_runtime.h>
#include <hip/hip_bf16.h>

// Problem constants (from reference): B=4, G=3, p=16, N=256, C=768, H=12, D=64
#define Bc 4
#define Gc 3
#define Pc 16
#define Nc 256
#define Cc_ 768
#define Hc 12
#define Dc 64
#define Mrows (Bc*Gc*Nc)      // 3072 tokens
#define KVcols (2*Cc_)        // 1536

// ---------------------------------------------------------------------------
// Tiled fp32 GEMM:  C[m][n] = sum_k A[m][k] * W[n][k]  (+ bias[n])
// A: (M,K) row-major, W: (N,K) row-major (i.e. torch Linear weight), C: (M,N)
// 64x64 tile, 256 threads, each thread 4x4 micro-tile, K-step 16.
// LDS stored k-major ([k][m]) so compute reads are float4 along m/n.
// ---------------------------------------------------------------------------
__global__ __launch_bounds__(256) void gemm_nt_64(
    const float* __restrict__ A, const float* __restrict__ W,
    float* __restrict__ C, const float* __restrict__ bias,
    int M, int Nn, int K)
{
    __shared__ float As[16][68];   // [k][m], pad keeps float4 alignment, 2-way max
    __shared__ float Bs[16][68];   // [k][n]

    const int tid  = threadIdx.x;
    const int m0   = blockIdx.y << 6;
    const int n0   = blockIdx.x << 6;
    const int tx   = tid & 15;          // n sub-tile
    const int ty   = tid >> 4;          // m sub-tile
    const int lrow = tid >> 2;          // 0..63 (row loaded by this thread)
    const int lk4  = (tid & 3) << 2;    // 0,4,8,12 (k offset)

    const float* Ap = A + (size_t)(m0 + lrow) * K + lk4;
    const float* Wp = W + (size_t)(n0 + lrow) * K + lk4;

    float acc[4][4] = {};

    for (int k0 = 0; k0 < K; k0 += 16) {
        const float4 av = *(const float4*)(Ap + k0);
        const float4 bv = *(const float4*)(Wp + k0);
        __syncthreads();   // previous iteration's LDS reads done
        As[lk4+0][lrow] = av.x; As[lk4+1][lrow] = av.y;
        As[lk4+2][lrow] = av.z; As[lk4+3][lrow] = av.w;
        Bs[lk4+0][lrow] = bv.x; Bs[lk4+1][lrow] = bv.y;
        Bs[lk4+2][lrow] = bv.z; Bs[lk4+3][lrow] = bv.w;
        __syncthreads();
        #pragma unroll
        for (int kk = 0; kk < 16; ++kk) {
            const float4 a4 = *(const float4*)&As[kk][ty << 2];
            const float4 b4 = *(const float4*)&Bs[kk][tx << 2];
            const float a[4] = {a4.x, a4.y, a4.z, a4.w};
            const float b[4] = {b4.x, b4.y, b4.z, b4.w};
            #pragma unroll
            for (int i = 0; i < 4; ++i)
                #pragma unroll
                for (int j = 0; j < 4; ++j)
                    acc[i][j] = fmaf(a[i], b[j], acc[i][j]);
        }
    }

    float bb[4] = {0.f, 0.f, 0.f, 0.f};
    if (bias) {
        const float4 b4 = *(const float4*)&bias[n0 + (tx << 2)];
        bb[0] = b4.x; bb[1] = b4.y; bb[2] = b4.z; bb[3] = b4.w;
    }
    #pragma unroll
    for (int i = 0; i < 4; ++i) {
        const int mrow = m0 + (ty << 2) + i;
        float4 r;
        r.x = acc[i][0] + bb[0];
        r.y = acc[i][1] + bb[1];
        r.z = acc[i][2] + bb[2];
        r.w = acc[i][3] + bb[3];
        *(float4*)&C[(size_t)mrow * Nn + n0 + (tx << 2)] = r;
    }
}

// ---------------------------------------------------------------------------
// Attention: one block (256 thr = 4 waves) per token t = (g*B+b)*N + n.
// Each wave handles heads {w, w+4, w+8}. Per head:
//   scores: lane = (j = lane&31, dhalf = lane>>5), partial dot over 32 dims,
//           combine with shfl_xor(32); softmax via shfl reduction.
//   PV:     lane = output dim d (0..63), p[j] broadcast via shfl.
// K/V are gathered from the per-token KV projection via the triplane index map.
// ---------------------------------------------------------------------------
__global__ __launch_bounds__(256) void attn_kernel(
    const float* __restrict__ Q,    // (Mrows, C) in x-order rows (b,g,n)
    const float* __restrict__ KV,   // (Mrows, 2C) in x-order rows; [0,C)=k, [C,2C)=v
    float* __restrict__ Oa)         // (Mrows, C) in out-order rows (g,b,n)
{
    const int t  = blockIdx.x;          // (g*4 + b)*256 + n
    const int g  = t >> 10;
    const int b  = (t >> 8) & 3;
    const int n  = t & 255;
    const int a  = n >> 4;
    const int bc = n & 15;

    __shared__ float qs[Cc_];
    __shared__ int   rows[32];

    const int qrow = (b * Gc + g) * Nc + n;   // x-order row of this token
    for (int i = threadIdx.x; i < Cc_; i += 256)
        qs[i] = Q[(size_t)qrow * Cc_ + i];

    if (threadIdx.x < 32) {
        const int j = threadIdx.x;
        int g1 = g + 1; if (g1 >= 3) g1 -= 3;
        int g2 = g + 2; if (g2 >= 3) g2 -= 3;
        rows[j] = (j < 16) ? ((b * Gc + g1) * Nc + a * 16 + j)
                           : ((b * Gc + g2) * Nc + (j - 16) * 16 + bc);
    }
    __syncthreads();

    const int wave = threadIdx.x >> 6;
    const int lane = threadIdx.x & 63;
    const int j    = lane & 31;
    const int dh   = lane >> 5;
    const size_t kvrow = (size_t)rows[j] * KVcols;

    for (int hh = 0; hh < 3; ++hh) {
        const int h = wave + hh * 4;          // heads 0..11
        // ---- scores ----
        const float* kp = KV + kvrow + h * Dc + dh * 32;
        const float* qp = qs + h * Dc + dh * 32;
        float s = 0.f;
        #pragma unroll
        for (int dd = 0; dd < 32; ++dd) s = fmaf(qp[dd], kp[dd], s);
        s += __shfl_xor(s, 32);               // full 64-dim dot (dup in halves)
        s *= 0.125f;                          // 1/sqrt(64)

        // ---- softmax over 32 ctx (halves hold identical values) ----
        float m = s;
        #pragma unroll
        for (int off = 16; off >= 1; off >>= 1) m = fmaxf(m, __shfl_xor(m, off));
        const float e = __expf(s - m);
        float l = e;
        #pragma unroll
        for (int off = 16; off >= 1; off >>= 1) l += __shfl_xor(l, off);
        const float pr = e / l;

        // ---- PV: lane = output dim ----
        float o = 0.f;
        #pragma unroll 8
        for (int jj = 0; jj < 32; ++jj) {
            const float pj = __shfl(pr, jj);  // p[jj] lives on lane jj
            const int rr = rows[jj];
            o = fmaf(pj, KV[(size_t)rr * KVcols + Cc_ + h * Dc + lane], o);
        }
        Oa[(size_t)t * Cc_ + h * Dc + lane] = o;
    }
}

extern "C" void kernel_launch(void* const* d_in, const int* in_sizes, int n_in,
                              void* d_out, int out_size, void* d_ws, size_t ws_size,
                              hipStream_t stream) {
    const float* x   = (const float*)d_in[0];   // (B,G,N,C)
    const float* wq  = (const float*)d_in[1];   // (C,C)
    const float* wkv = (const float*)d_in[2];   // (2C,C)
    const float* pw  = (const float*)d_in[3];   // (C,C)
    const float* pb  = (const float*)d_in[4];   // (C,)
    float* out = (float*)d_out;

    float* Q   = (float*)d_ws;                  // 3072*768
    float* KV  = Q  + (size_t)Mrows * Cc_;      // 3072*1536
    float* ATT = KV + (size_t)Mrows * KVcols;   // 3072*768

    const dim3 blk(256);

    // Q = x @ wq^T      (x-order rows)
    gemm_nt_64<<<dim3(Cc_ / 64, Mrows / 64), blk, 0, stream>>>(
        x, wq, Q, nullptr, Mrows, Cc_, Cc_);
    // KV = x @ w_kv^T   (x-order rows) — projects each token ONCE (32x less
    // work than projecting the materialized context)
    gemm_nt_64<<<dim3(KVcols / 64, Mrows / 64), blk, 0, stream>>>(
        x, wkv, KV, nullptr, Mrows, KVcols, Cc_);
    // attention with gathered K/V, writes out-order rows
    attn_kernel<<<dim3(Mrows), blk, 0, stream>>>(Q, KV, ATT);
    // out = ATT @ proj_w^T + proj_b   (d_out layout == flat (g,b,n,c))
    gemm_nt_64<<<dim3(Cc_ / 64, Mrows / 64), blk, 0, stream>>>(
        ATT, pw, out, pb, Mrows, Cc_, Cc_);
}

// Round 5
// 110.145 us; speedup vs baseline: 2.7102x; 2.7040x over previous
//
#include <hip/hip_runtime.h>
#include <hip/hip_bf16.h>

// Problem constants: B=4, G=3, p=16, N=256, C=768, H=12, D=64
#define Bc 4
#define Gc 3
#define Pc 16
#define Nc 256
#define Cc_ 768
#define Hc 12
#define Dc 64
#define Mrows (Bc*Gc*Nc)      // 3072 tokens
#define KVcols (2*Cc_)        // 1536

typedef _Float16 half_t;
typedef __attribute__((ext_vector_type(8))) _Float16 f16x8;
typedef __attribute__((ext_vector_type(4))) float f32x4;

#define XN   (Bc*Gc*Nc*Cc_)   // 2359296
#define WQN  (Cc_*Cc_)        // 589824
#define WKVN (2*Cc_*Cc_)      // 1179648
#define PWN  (Cc_*Cc_)        // 589824

// ---------------------------------------------------------------------------
// fp32 -> f16 conversion for x + all three weight matrices, one launch.
// 8 elements/thread, all region boundaries are multiples of 8.
// ---------------------------------------------------------------------------
__global__ __launch_bounds__(256) void cvt_all(
    const float* __restrict__ x, const float* __restrict__ wq,
    const float* __restrict__ wkv, const float* __restrict__ pw,
    half_t* __restrict__ x16, half_t* __restrict__ wq16,
    half_t* __restrict__ wkv16, half_t* __restrict__ pw16)
{
    const size_t e = ((size_t)blockIdx.x * 256 + threadIdx.x) * 8;
    const float* s; half_t* d;
    if (e < XN)                    { s = x   + e;                     d = x16   + e; }
    else if (e < XN + WQN)         { s = wq  + (e - XN);              d = wq16  + (e - XN); }
    else if (e < XN + WQN + WKVN)  { s = wkv + (e - XN - WQN);        d = wkv16 + (e - XN - WQN); }
    else                           { s = pw  + (e - XN - WQN - WKVN); d = pw16  + (e - XN - WQN - WKVN); }
    const float4 a = *(const float4*)s;
    const float4 b = *(const float4*)(s + 4);
    f16x8 o;
    o[0] = (half_t)a.x; o[1] = (half_t)a.y; o[2] = (half_t)a.z; o[3] = (half_t)a.w;
    o[4] = (half_t)b.x; o[5] = (half_t)b.y; o[6] = (half_t)b.z; o[7] = (half_t)b.w;
    *(f16x8*)d = o;
}

// ---------------------------------------------------------------------------
// f16 MFMA GEMM:  C[m][n] = sum_k A[m][k]*W[n][k]  (+ bias[n])
// A: (M,K) f16 row-major, W: (N,K) f16 row-major. OutT in {half_t, float}.
// 128x128 tile, BK=32, 256 thr = 4 waves (2x2 of 64x64), mfma 16x16x32.
// global_load_lds(16B) stages into LDS laid out [kgroup][row][8 f16] so that
//  - each wave-instruction writes 1KB linearly (lane*16) as required (m104)
//  - ds_read_b128 fragment reads are 2-way bank aliased (free, m136)
// Minimum 2-phase schedule per T3: stage(next) after barrier, compute cur.
// ---------------------------------------------------------------------------
template<typename OutT, bool BIAS>
__global__ __launch_bounds__(256) void gemm16(
    const half_t* __restrict__ A, const half_t* __restrict__ W,
    OutT* __restrict__ C, const float* __restrict__ bias,
    int M, int Nn, int K)
{
    // [buf][A/B][kgroup][row][8 f16]  = 32 KiB
    __shared__ __attribute__((aligned(16))) half_t sm[2][2][4][128][8];

    const int tid = threadIdx.x;
    const int w   = tid >> 6;          // wave 0..3
    const int l   = tid & 63;
    const int wm  = w >> 1;            // 0..1  (m sub-tile)
    const int wn  = w & 1;             // 0..1  (n sub-tile)
    const int m0  = blockIdx.y << 7;
    const int n0  = blockIdx.x << 7;

    f32x4 acc[4][4] = {};

    // stage tile (k0): 8KB A + 8KB B; per wave 2 chunks each.
    // chunk c (0..7): kg = c>>1, rows (c&1)*64 + lane
    auto stage = [&](int buf, int k0) {
        #pragma unroll
        for (int i = 0; i < 2; ++i) {
            const int c   = w * 2 + i;
            const int kg  = c >> 1;
            const int r0  = (c & 1) * 64;
            const half_t* ga = A + (size_t)(m0 + r0 + l) * K + k0 + kg * 8;
            const half_t* gb = W + (size_t)(n0 + r0 + l) * K + k0 + kg * 8;
            __builtin_amdgcn_global_load_lds(
                (__attribute__((address_space(1))) void*)ga,
                (__attribute__((address_space(3))) void*)&sm[buf][0][kg][r0][0],
                16, 0, 0);
            __builtin_amdgcn_global_load_lds(
                (__attribute__((address_space(1))) void*)gb,
                (__attribute__((address_space(3))) void*)&sm[buf][1][kg][r0][0],
                16, 0, 0);
        }
    };

    const int NT = K >> 5;             // 24 for K=768
    stage(0, 0);
    int cur = 0;
    const int kg = l >> 4;             // 0..3
    const int lr = l & 15;

    for (int t = 0; t < NT; ++t) {
        __syncthreads();               // drains vmcnt: buf[cur] staged; prev reads done
        if (t + 1 < NT) stage(cur ^ 1, (t + 1) << 5);

        f16x8 af[4], bf[4];
        #pragma unroll
        for (int mi = 0; mi < 4; ++mi)
            af[mi] = *(const f16x8*)&sm[cur][0][kg][wm * 64 + mi * 16 + lr][0];
        #pragma unroll
        for (int ni = 0; ni < 4; ++ni)
            bf[ni] = *(const f16x8*)&sm[cur][1][kg][wn * 64 + ni * 16 + lr][0];

        #pragma unroll
        for (int mi = 0; mi < 4; ++mi)
            #pragma unroll
            for (int ni = 0; ni < 4; ++ni)
                acc[mi][ni] = __builtin_amdgcn_mfma_f32_16x16x32_f16(
                    af[mi], bf[ni], acc[mi][ni], 0, 0, 0);
        cur ^= 1;
    }

    // epilogue: C/D layout col = lane&15, row = (lane>>4)*4 + reg (m89-verified)
    const int lq = l >> 4;
    #pragma unroll
    for (int ni = 0; ni < 4; ++ni) {
        const int gcol = n0 + wn * 64 + ni * 16 + lr;
        const float bv = BIAS ? bias[gcol] : 0.f;
        #pragma unroll
        for (int mi = 0; mi < 4; ++mi) {
            const int grow = m0 + wm * 64 + mi * 16 + lq * 4;
            #pragma unroll
            for (int r = 0; r < 4; ++r)
                C[(size_t)(grow + r) * Nn + gcol] = (OutT)(acc[mi][ni][r] + bv);
        }
    }
}

// ---------------------------------------------------------------------------
// Attention: one block (4 waves) per token t=(g*B+b)*N+n; wave handles heads
// {w, w+4, w+8}. Q/KV are f16 (fp32 math), K/V gathered via triplane map.
// ---------------------------------------------------------------------------
__global__ __launch_bounds__(256) void attn_kernel(
    const half_t* __restrict__ Q,    // (Mrows, C) f16, x-order rows (b,g,n)
    const half_t* __restrict__ KV,   // (Mrows, 2C) f16, x-order; [0,C)=k [C,2C)=v
    half_t* __restrict__ Oa)         // (Mrows, C) f16, out-order rows (g,b,n)
{
    const int t  = blockIdx.x;
    const int g  = t >> 10;
    const int b  = (t >> 8) & 3;
    const int n  = t & 255;
    const int a  = n >> 4;
    const int bc = n & 15;

    __shared__ float qs[Cc_];
    __shared__ int   rows[32];

    const int qrow = (b * Gc + g) * Nc + n;
    if (threadIdx.x < 96) {
        const f16x8 v = ((const f16x8*)(Q + (size_t)qrow * Cc_))[threadIdx.x];
        #pragma unroll
        for (int jj = 0; jj < 8; ++jj) qs[threadIdx.x * 8 + jj] = (float)v[jj];
    }
    if (threadIdx.x < 32) {
        const int j = threadIdx.x;
        int g1 = g + 1; if (g1 >= 3) g1 -= 3;
        int g2 = g + 2; if (g2 >= 3) g2 -= 3;
        rows[j] = (j < 16) ? ((b * Gc + g1) * Nc + a * 16 + j)
                           : ((b * Gc + g2) * Nc + (j - 16) * 16 + bc);
    }
    __syncthreads();

    const int wave = threadIdx.x >> 6;
    const int lane = threadIdx.x & 63;
    const int j    = lane & 31;
    const int dh   = lane >> 5;
    const size_t kvrow = (size_t)rows[j] * KVcols;

    for (int hh = 0; hh < 3; ++hh) {
        const int h = wave + hh * 4;
        // ---- scores: lane=(j ctx, dh half), vectorized f16 K reads ----
        const f16x8* kp = (const f16x8*)(KV + kvrow + h * Dc + dh * 32);
        const float* qp = qs + h * Dc + dh * 32;
        float s = 0.f;
        #pragma unroll
        for (int c = 0; c < 4; ++c) {
            const f16x8 k8 = kp[c];
            #pragma unroll
            for (int e = 0; e < 8; ++e) s = fmaf(qp[c * 8 + e], (float)k8[e], s);
        }
        s += __shfl_xor(s, 32);
        s *= 0.125f;                         // 1/sqrt(64)

        // ---- softmax over 32 ctx (halves identical) ----
        float m = s;
        #pragma unroll
        for (int off = 16; off >= 1; off >>= 1) m = fmaxf(m, __shfl_xor(m, off));
        const float e = __expf(s - m);
        float lsum = e;
        #pragma unroll
        for (int off = 16; off >= 1; off >>= 1) lsum += __shfl_xor(lsum, off);
        const float pr = e / lsum;

        // ---- PV: lane = output dim ----
        float o = 0.f;
        #pragma unroll 8
        for (int jj = 0; jj < 32; ++jj) {
            const float pj = __shfl(pr, jj);
            o = fmaf(pj, (float)KV[(size_t)rows[jj] * KVcols + Cc_ + h * Dc + lane], o);
        }
        Oa[(size_t)t * Cc_ + h * Dc + lane] = (half_t)o;
    }
}

extern "C" void kernel_launch(void* const* d_in, const int* in_sizes, int n_in,
                              void* d_out, int out_size, void* d_ws, size_t ws_size,
                              hipStream_t stream) {
    const float* x   = (const float*)d_in[0];
    const float* wq  = (const float*)d_in[1];
    const float* wkv = (const float*)d_in[2];
    const float* pw  = (const float*)d_in[3];
    const float* pb  = (const float*)d_in[4];
    float* out = (float*)d_out;

    // f16 workspace (28.3 MB total)
    half_t* x16   = (half_t*)d_ws;
    half_t* wq16  = x16   + XN;
    half_t* wkv16 = wq16  + WQN;
    half_t* pw16  = wkv16 + WKVN;
    half_t* Q16   = pw16  + PWN;                       // 3072*768
    half_t* KV16  = Q16   + (size_t)Mrows * Cc_;       // 3072*1536
    half_t* ATT16 = KV16  + (size_t)Mrows * KVcols;    // 3072*768

    const dim3 blk(256);

    // 1. fp32 -> f16 for x and all weights (4.72M elems / 8 per thread)
    cvt_all<<<dim3((XN + WQN + WKVN + PWN) / 8 / 256), blk, 0, stream>>>(
        x, wq, wkv, pw, x16, wq16, wkv16, pw16);

    // 2. Q16 = x16 @ wq16^T   (x-order rows)
    gemm16<half_t, false><<<dim3(Cc_ / 128, Mrows / 128), blk, 0, stream>>>(
        x16, wq16, Q16, nullptr, Mrows, Cc_, Cc_);

    // 3. KV16 = x16 @ wkv16^T (projects each token ONCE; 32x less than ref)
    gemm16<half_t, false><<<dim3(KVcols / 128, Mrows / 128), blk, 0, stream>>>(
        x16, wkv16, KV16, nullptr, Mrows, KVcols, Cc_);

    // 4. attention with gathered K/V, writes out-order rows (f16)
    attn_kernel<<<dim3(Mrows), blk, 0, stream>>>(Q16, KV16, ATT16);

    // 5. out = ATT16 @ pw16^T + pb  (fp32 epilogue straight into d_out)
    gemm16<float, true><<<dim3(Cc_ / 128, Mrows / 128), blk, 0, stream>>>(
        ATT16, pw16, out, pb, Mrows, Cc_, Cc_);
}

// Round 6
// 85.544 us; speedup vs baseline: 3.4895x; 1.2876x over previous
//
#include <hip/hip_runtime.h>
#include <hip/hip_bf16.h>

// Problem constants: B=4, G=3, p=16, N=256, C=768, H=12, D=64
#define Bc 4
#define Gc 3
#define Nc 256
#define Cc_ 768
#define Dc 64
#define Mrows (Bc*Gc*Nc)      // 3072 tokens
#define QKVc (3*Cc_)          // 2304 fused output cols: [q | k | v]
#define Koff Cc_              // k starts at col 768
#define Voff (2*Cc_)          // v starts at col 1536

typedef _Float16 half_t;
typedef __attribute__((ext_vector_type(8))) _Float16 f16x8;
typedef __attribute__((ext_vector_type(4))) float f32x4;

#define XN   (Mrows*Cc_)      // 2359296
#define WQN  (Cc_*Cc_)        // 589824
#define WKVN (2*Cc_*Cc_)      // 1179648
#define PWN  (Cc_*Cc_)        // 589824

// ---------------------------------------------------------------------------
// fp32 -> f16 conversion for x + all three weight matrices, one launch.
// wq16/wkv16 are written CONTIGUOUSLY so they form one (2304,768) weight.
// ---------------------------------------------------------------------------
__global__ __launch_bounds__(256) void cvt_all(
    const float* __restrict__ x, const float* __restrict__ wq,
    const float* __restrict__ wkv, const float* __restrict__ pw,
    half_t* __restrict__ x16, half_t* __restrict__ wq16,
    half_t* __restrict__ wkv16, half_t* __restrict__ pw16)
{
    const size_t e = ((size_t)blockIdx.x * 256 + threadIdx.x) * 8;
    const float* s; half_t* d;
    if (e < XN)                    { s = x   + e;                     d = x16   + e; }
    else if (e < XN + WQN)         { s = wq  + (e - XN);              d = wq16  + (e - XN); }
    else if (e < XN + WQN + WKVN)  { s = wkv + (e - XN - WQN);        d = wkv16 + (e - XN - WQN); }
    else                           { s = pw  + (e - XN - WQN - WKVN); d = pw16  + (e - XN - WQN - WKVN); }
    const float4 a = *(const float4*)s;
    const float4 b = *(const float4*)(s + 4);
    f16x8 o;
    o[0] = (half_t)a.x; o[1] = (half_t)a.y; o[2] = (half_t)a.z; o[3] = (half_t)a.w;
    o[4] = (half_t)b.x; o[5] = (half_t)b.y; o[6] = (half_t)b.z; o[7] = (half_t)b.w;
    *(f16x8*)d = o;
}

// ---------------------------------------------------------------------------
// f16 MFMA GEMM:  C[m][n] = sum_k A[m][k]*W[n][k]  (+ bias[n])
// 128x128 tile, BK=32, 256 thr = 4 waves (2x2 of 64x64), mfma 16x16x32.
// T3/T4-lite: 3 LDS buffers, stage 2 tiles ahead via global_load_lds(16B),
// counted `s_waitcnt vmcnt(4)` + raw s_barrier — never drains vmcnt(0) in
// the main loop (the m201 discipline). Stage(t+2) is issued AFTER the
// barrier: between barriers waves read buf[t%3] and write buf[(t+2)%3] only.
// ---------------------------------------------------------------------------
template<typename OutT, bool BIAS>
__global__ __launch_bounds__(256) void gemm16(
    const half_t* __restrict__ A, const half_t* __restrict__ W,
    OutT* __restrict__ C, const float* __restrict__ bias,
    int M, int Nn, int K)
{
    // [buf][A/B][kgroup][row][8 f16] = 48 KiB
    __shared__ __attribute__((aligned(16))) half_t sm[3][2][4][128][8];

    const int tid = threadIdx.x;
    const int w   = tid >> 6;          // wave 0..3
    const int l   = tid & 63;
    const int wm  = w >> 1;            // m sub-tile
    const int wn  = w & 1;             // n sub-tile
    const int m0  = blockIdx.y << 7;
    const int n0  = blockIdx.x << 7;

    f32x4 acc[4][4] = {};

    // stage one 128x32 A-tile + B-tile: 4 global_load_lds(16B) per thread
    auto stage = [&](int buf, int k0) {
        #pragma unroll
        for (int i = 0; i < 2; ++i) {
            const int c   = w * 2 + i;
            const int kg  = c >> 1;
            const int r0  = (c & 1) * 64;
            const half_t* ga = A + (size_t)(m0 + r0 + l) * K + k0 + kg * 8;
            const half_t* gb = W + (size_t)(n0 + r0 + l) * K + k0 + kg * 8;
            __builtin_amdgcn_global_load_lds(
                (__attribute__((address_space(1))) void*)ga,
                (__attribute__((address_space(3))) void*)&sm[buf][0][kg][r0][0],
                16, 0, 0);
            __builtin_amdgcn_global_load_lds(
                (__attribute__((address_space(1))) void*)gb,
                (__attribute__((address_space(3))) void*)&sm[buf][1][kg][r0][0],
                16, 0, 0);
        }
    };

    const int NT = K >> 5;             // 24 for K=768 (always >= 2 here)
    stage(0, 0);
    stage(1, 32);

    const int kg = l >> 4;             // 0..3
    const int lr = l & 15;
    int cur = 0;

    for (int t = 0; t < NT; ++t) {
        // retire exactly stage(t) (own wave), allow stage(t+1) in flight
        if (t + 1 < NT) asm volatile("s_waitcnt vmcnt(4)" ::: "memory");
        else            asm volatile("s_waitcnt vmcnt(0)" ::: "memory");
        __builtin_amdgcn_s_barrier();
        if (t + 2 < NT) {
            int nb = cur + 2; if (nb >= 3) nb -= 3;
            stage(nb, (t + 2) << 5);
        }

        f16x8 af[4], bf[4];
        #pragma unroll
        for (int mi = 0; mi < 4; ++mi)
            af[mi] = *(const f16x8*)&sm[cur][0][kg][wm * 64 + mi * 16 + lr][0];
        #pragma unroll
        for (int ni = 0; ni < 4; ++ni)
            bf[ni] = *(const f16x8*)&sm[cur][1][kg][wn * 64 + ni * 16 + lr][0];

        #pragma unroll
        for (int mi = 0; mi < 4; ++mi)
            #pragma unroll
            for (int ni = 0; ni < 4; ++ni)
                acc[mi][ni] = __builtin_amdgcn_mfma_f32_16x16x32_f16(
                    af[mi], bf[ni], acc[mi][ni], 0, 0, 0);

        cur = (cur == 2) ? 0 : cur + 1;
    }

    // epilogue: C/D layout col = lane&15, row = (lane>>4)*4 + reg (m89)
    const int lq = l >> 4;
    #pragma unroll
    for (int ni = 0; ni < 4; ++ni) {
        const int gcol = n0 + wn * 64 + ni * 16 + lr;
        const float bv = BIAS ? bias[gcol] : 0.f;
        #pragma unroll
        for (int mi = 0; mi < 4; ++mi) {
            const int grow = m0 + wm * 64 + mi * 16 + lq * 4;
            #pragma unroll
            for (int r = 0; r < 4; ++r)
                C[(size_t)(grow + r) * Nn + gcol] = (OutT)(acc[mi][ni][r] + bv);
        }
    }
}

// ---------------------------------------------------------------------------
// Attention: one block (4 waves) per token t=(g*B+b)*N+n; wave handles heads
// {w, w+4, w+8}. Q/K/V all come from the fused QKV buffer (f16, fp32 math).
// ---------------------------------------------------------------------------
__global__ __launch_bounds__(256) void attn_kernel(
    const half_t* __restrict__ QKV,  // (Mrows, 2304) f16 x-order; [q|k|v]
    half_t* __restrict__ Oa)         // (Mrows, C) f16, out-order rows (g,b,n)
{
    const int t  = blockIdx.x;
    const int g  = t >> 10;
    const int b  = (t >> 8) & 3;
    const int n  = t & 255;
    const int a  = n >> 4;
    const int bc = n & 15;

    __shared__ float qs[Cc_];
    __shared__ int   rows[32];

    const int qrow = (b * Gc + g) * Nc + n;
    if (threadIdx.x < 96) {
        const f16x8 v = ((const f16x8*)(QKV + (size_t)qrow * QKVc))[threadIdx.x];
        #pragma unroll
        for (int jj = 0; jj < 8; ++jj) qs[threadIdx.x * 8 + jj] = (float)v[jj];
    }
    if (threadIdx.x < 32) {
        const int j = threadIdx.x;
        int g1 = g + 1; if (g1 >= 3) g1 -= 3;
        int g2 = g + 2; if (g2 >= 3) g2 -= 3;
        rows[j] = (j < 16) ? ((b * Gc + g1) * Nc + a * 16 + j)
                           : ((b * Gc + g2) * Nc + (j - 16) * 16 + bc);
    }
    __syncthreads();

    const int wave = threadIdx.x >> 6;
    const int lane = threadIdx.x & 63;
    const int j    = lane & 31;
    const int dh   = lane >> 5;
    const size_t kvrow = (size_t)rows[j] * QKVc;

    for (int hh = 0; hh < 3; ++hh) {
        const int h = wave + hh * 4;
        // ---- scores: lane=(j ctx, dh half), vectorized f16 K reads ----
        const f16x8* kp = (const f16x8*)(QKV + kvrow + Koff + h * Dc + dh * 32);
        const float* qp = qs + h * Dc + dh * 32;
        float s = 0.f;
        #pragma unroll
        for (int c = 0; c < 4; ++c) {
            const f16x8 k8 = kp[c];
            #pragma unroll
            for (int e = 0; e < 8; ++e) s = fmaf(qp[c * 8 + e], (float)k8[e], s);
        }
        s += __shfl_xor(s, 32);
        s *= 0.125f;                         // 1/sqrt(64)

        // ---- softmax over 32 ctx (halves identical) ----
        float m = s;
        #pragma unroll
        for (int off = 16; off >= 1; off >>= 1) m = fmaxf(m, __shfl_xor(m, off));
        const float e = __expf(s - m);
        float lsum = e;
        #pragma unroll
        for (int off = 16; off >= 1; off >>= 1) lsum += __shfl_xor(lsum, off);
        const float pr = e / lsum;

        // ---- PV: lane = output dim ----
        float o = 0.f;
        #pragma unroll 8
        for (int jj = 0; jj < 32; ++jj) {
            const float pj = __shfl(pr, jj);
            o = fmaf(pj, (float)QKV[(size_t)rows[jj] * QKVc + Voff + h * Dc + lane], o);
        }
        Oa[(size_t)t * Cc_ + h * Dc + lane] = (half_t)o;
    }
}

extern "C" void kernel_launch(void* const* d_in, const int* in_sizes, int n_in,
                              void* d_out, int out_size, void* d_ws, size_t ws_size,
                              hipStream_t stream) {
    const float* x   = (const float*)d_in[0];
    const float* wq  = (const float*)d_in[1];
    const float* wkv = (const float*)d_in[2];
    const float* pw  = (const float*)d_in[3];
    const float* pb  = (const float*)d_in[4];
    float* out = (float*)d_out;

    // f16 workspace (~28.3 MB)
    half_t* x16   = (half_t*)d_ws;
    half_t* w3    = x16 + XN;                      // [wq; wkv] = (2304, 768)
    half_t* pw16  = w3 + WQN + WKVN;
    half_t* QKV16 = pw16 + PWN;                    // (3072, 2304)
    half_t* ATT16 = QKV16 + (size_t)Mrows * QKVc;  // (3072, 768)

    const dim3 blk(256);

    // 1. fp32 -> f16 (x + weights); wq/wkv land contiguously in w3
    cvt_all<<<dim3((XN + WQN + WKVN + PWN) / 8 / 256), blk, 0, stream>>>(
        x, wq, wkv, pw, x16, w3, w3 + WQN, pw16);

    // 2. QKV = x16 @ [wq;wkv]^T  — one fused GEMM (3072 x 2304 x 768)
    gemm16<half_t, false><<<dim3(QKVc / 128, Mrows / 128), blk, 0, stream>>>(
        x16, w3, QKV16, nullptr, Mrows, QKVc, Cc_);

    // 3. attention with gathered K/V, writes out-order rows (f16)
    attn_kernel<<<dim3(Mrows), blk, 0, stream>>>(QKV16, ATT16);

    // 4. out = ATT16 @ pw16^T + pb  (fp32 epilogue straight into d_out)
    gemm16<float, true><<<dim3(Cc_ / 128, Mrows / 128), blk, 0, stream>>>(
        ATT16, pw16, out, pb, Mrows, Cc_, Cc_);
}